// Round 2
// baseline (111.585 us; speedup 1.0000x reference)
//
#include <hip/hip_runtime.h>
#include <hip/hip_bf16.h>

// ---------------------------------------------------------------------------
// Model_51453708206406: Qwen-VL-style fast_pos_embed_interpolate + MRoPE
// cos/sin tables. Outputs (concatenated flat, FLOAT32):
//   [0] patch_pos_embeds [46080, 1152]
//   [1] cos(emb)         [46080, 128]
//   [2] sin(emb)         [46080, 128]
// Grid (static metadata per reference): {1,64,64},{4,48,48},{8,32,64},{16,32,32}
// ---------------------------------------------------------------------------

// --------------------------- patch pos embeds ------------------------------
// one thread = 4 consecutive channels (16B f32 store) of one token
template <int T, int H, int W, int OFF>
__global__ __launch_bounds__(256) void patch_kernel(
    const float* __restrict__ tab,        // [35*35, 1152]
    float* __restrict__ out)              // f32 [46080, 1152]
{
    constexpr int HW   = H * W;
    constexpr int TOKS = T * HW;
    constexpr int C4   = 1152 / 4;        // 288 chunks of 4 channels
    constexpr int WB   = W / 2;

    int idx = blockIdx.x * 256 + threadIdx.x;
    if (idx >= TOKS * C4) return;

    int tok = idx / C4;
    int c4  = idx - tok * C4;
    int rem = tok % HW;                   // frame-local index (frames identical)

    // inverse of the (bh, bw, i, j) merged-block ordering:
    // rem = ((bh*WB + bw)<<2) + (i<<1) + j ; row = 2bh+i, col = 2bw+j
    int j  = rem & 1;
    int i  = (rem >> 1) & 1;
    int b  = rem >> 2;
    int bw = b % WB;
    int bh = b / WB;
    int row = (bh << 1) + i;
    int col = (bw << 1) + j;

    // linspace(0, 34, H)[row], linspace(0, 34, W)[col]
    float hx = (float)row * (float)(34.0 / (H - 1));
    float wx = (float)col * (float)(34.0 / (W - 1));
    int hf = (int)hx, wf = (int)wx;
    float dh = hx - (float)hf, dw = wx - (float)wf;
    int hc = min(hf + 1, 34), wc = min(wf + 1, 34);

    float w00 = (1.f - dh) * (1.f - dw);
    float w01 = (1.f - dh) * dw;
    float w10 = dh * (1.f - dw);
    float w11 = dh * dw;

    const float4 a = *((const float4*)(tab + (hf * 35 + wf) * 1152) + c4);
    const float4 bb= *((const float4*)(tab + (hf * 35 + wc) * 1152) + c4);
    const float4 c = *((const float4*)(tab + (hc * 35 + wf) * 1152) + c4);
    const float4 d = *((const float4*)(tab + (hc * 35 + wc) * 1152) + c4);

    float4 o;
    o.x = w00 * a.x + w01 * bb.x + w10 * c.x + w11 * d.x;
    o.y = w00 * a.y + w01 * bb.y + w10 * c.y + w11 * d.y;
    o.z = w00 * a.z + w01 * bb.z + w10 * c.z + w11 * d.z;
    o.w = w00 * a.w + w01 * bb.w + w10 * c.w + w11 * d.w;

    *(float4*)(out + (size_t)(OFF + tok) * 1152 + (c4 << 2)) = o;
}

// ------------------------------ cos / sin ----------------------------------
// one thread = 4 channels (d0=4*l4 .. +3) of one token; writes both
// duplicated 64-wide halves of cos and sin as float4.
template <int T, int H, int W, int OFF>
__global__ __launch_bounds__(256) void rope_kernel(
    const float* __restrict__ invf,       // [32]
    float* __restrict__ cosO,             // f32 [46080, 128]
    float* __restrict__ sinO)             // f32 [46080, 128]
{
    constexpr int HW   = H * W;
    constexpr int TOKS = T * HW;
    constexpr int WB   = W / 2;

    int idx = blockIdx.x * 256 + threadIdx.x;
    if (idx >= TOKS * 16) return;

    int tok = idx >> 4;
    int l4  = idx & 15;                   // channel-quad index, d0 = 4*l4 in [0,64)
    int rem = tok % HW;

    int j  = rem & 1;
    int i  = (rem >> 1) & 1;
    int b  = rem >> 2;
    int bw = b % WB;
    int bh = b / WB;
    int row = (bh << 1) + i;
    int col = (bw << 1) + j;

    // d0 < 32 (l4 < 8) -> row, else col; quad never crosses the boundary
    float fp = (float)((l4 < 8) ? row : col);
    float4 iv = *((const float4*)invf + (l4 & 7));

    float s0, c0, s1, c1, s2, c2, s3, c3;
    __sincosf(fp * iv.x, &s0, &c0);
    __sincosf(fp * iv.y, &s1, &c1);
    __sincosf(fp * iv.z, &s2, &c2);
    __sincosf(fp * iv.w, &s3, &c3);

    size_t base = (size_t)(OFF + tok) * 128 + (l4 << 2);
    float4 cv = {c0, c1, c2, c3};
    float4 sv = {s0, s1, s2, s3};
    *(float4*)(cosO + base)      = cv;    // first 64-wide half
    *(float4*)(cosO + base + 64) = cv;    // duplicated second half
    *(float4*)(sinO + base)      = sv;
    *(float4*)(sinO + base + 64) = sv;
}

// ---------------------------------------------------------------------------

extern "C" void kernel_launch(void* const* d_in, const int* in_sizes, int n_in,
                              void* d_out, int out_size, void* d_ws, size_t ws_size,
                              hipStream_t stream) {
    // inputs: [0] grid_thw (int, static), [1] pos_embed_weight f32 [1225,1152],
    //         [2] inv_freq f32 [32], [3] spatial_merge_size, [4] num_grid_per_side
    const float* tab  = (const float*)d_in[1];
    const float* invf = (const float*)d_in[2];
    float* out = (float*)d_out;

    // token offsets: img0=0 (4096), img1=4096 (9216), img2=13312 (16384),
    // img3=29696 (16384); total 46080
    constexpr size_t NTOK = 46080;
    float* cosO = out + NTOK * 1152;
    float* sinO = cosO + NTOK * 128;

    // ---- patch pos embeds: threads = TOKS*288 ----
    patch_kernel<1, 64, 64, 0>    <<<(4096  * 288) / 256, 256, 0, stream>>>(tab, out);
    patch_kernel<4, 48, 48, 4096> <<<(9216  * 288) / 256, 256, 0, stream>>>(tab, out);
    patch_kernel<8, 32, 64, 13312><<<(16384 * 288) / 256, 256, 0, stream>>>(tab, out);
    patch_kernel<16,32, 32, 29696><<<(16384 * 288) / 256, 256, 0, stream>>>(tab, out);

    // ---- cos/sin: threads = TOKS*16 ----
    rope_kernel<1, 64, 64, 0>    <<<(4096  * 16) / 256, 256, 0, stream>>>(invf, cosO, sinO);
    rope_kernel<4, 48, 48, 4096> <<<(9216  * 16) / 256, 256, 0, stream>>>(invf, cosO, sinO);
    rope_kernel<8, 32, 64, 13312><<<(16384 * 16) / 256, 256, 0, stream>>>(invf, cosO, sinO);
    rope_kernel<16,32, 32, 29696><<<(16384 * 16) / 256, 256, 0, stream>>>(invf, cosO, sinO);
}

// Round 3
// 58.391 us; speedup vs baseline: 1.9110x; 1.9110x over previous
//
#include <hip/hip_runtime.h>

// ---------------------------------------------------------------------------
// Model_51453708206406: fast_pos_embed_interpolate + MRoPE cos/sin (f32 out).
// Outputs concatenated: [46080,1152] pe | [46080,128] cos | [46080,128] sin.
// Static grid: {1,64,64},{4,48,48},{8,32,64},{16,32,32}; merge m=2, G=35.
//
// Key structure: frames within an image are identical (jnp.tile over t), so
// compute only frame 0 (9472 unique tokens) and replicate stores across t.
// Cuts table read traffic 849 MB -> 175 MB; single fused dispatch.
// ---------------------------------------------------------------------------

template <int T, int H, int W, int OFF>
__device__ __forceinline__ void patch_body(int b, const float* __restrict__ tab,
                                           float* __restrict__ out) {
    constexpr int C4 = 1152 / 4;          // 288 channel-quads
    constexpr int HW = H * W;
    constexpr int WB = W / 2;

    int idx = b * 256 + (int)threadIdx.x; // < HW*288 (exact multiple of 256)
    int tok = idx / C4;                   // frame-0 token in merged order
    int c4  = idx - tok * C4;

    // invert merged-block ordering: tok = ((bh*WB+bw)<<2)+(i<<1)+j
    int j  = tok & 1;
    int i  = (tok >> 1) & 1;
    int blk = tok >> 2;
    int bw = blk % WB;
    int bh = blk / WB;
    int row = (bh << 1) + i;
    int col = (bw << 1) + j;

    // linspace(0,34,H)[row], linspace(0,34,W)[col]
    float hx = (float)row * (float)(34.0 / (H - 1));
    float wx = (float)col * (float)(34.0 / (W - 1));
    int hf = (int)hx, wf = (int)wx;
    float dh = hx - (float)hf, dw = wx - (float)wf;
    int hc = min(hf + 1, 34), wc = min(wf + 1, 34);

    float w00 = (1.f - dh) * (1.f - dw);
    float w01 = (1.f - dh) * dw;
    float w10 = dh * (1.f - dw);
    float w11 = dh * dw;

    const float4 a = *((const float4*)(tab + (hf * 35 + wf) * 1152) + c4);
    const float4 bq= *((const float4*)(tab + (hf * 35 + wc) * 1152) + c4);
    const float4 c = *((const float4*)(tab + (hc * 35 + wf) * 1152) + c4);
    const float4 d = *((const float4*)(tab + (hc * 35 + wc) * 1152) + c4);

    float4 o;
    o.x = w00 * a.x + w01 * bq.x + w10 * c.x + w11 * d.x;
    o.y = w00 * a.y + w01 * bq.y + w10 * c.y + w11 * d.y;
    o.z = w00 * a.z + w01 * bq.z + w10 * c.z + w11 * d.z;
    o.w = w00 * a.w + w01 * bq.w + w10 * c.w + w11 * d.w;

    float* dst = out + (size_t)(OFF + tok) * 1152 + (c4 << 2);
    #pragma unroll
    for (int f = 0; f < T; ++f)           // frames are identical copies
        *(float4*)(dst + (size_t)f * (HW * 1152)) = o;
}

template <int T, int H, int W, int OFF>
__device__ __forceinline__ void rope_body(int b, const float* __restrict__ invf,
                                          float* __restrict__ cosO,
                                          float* __restrict__ sinO) {
    constexpr int HW = H * W;
    constexpr int WB = W / 2;

    int idx = b * 256 + (int)threadIdx.x; // < HW*16 (exact multiple of 256)
    int tok = idx >> 4;
    int l4  = idx & 15;                   // channel-quad, d0 = 4*l4 in [0,64)

    int j  = tok & 1;
    int i  = (tok >> 1) & 1;
    int blk = tok >> 2;
    int bw = blk % WB;
    int bh = blk / WB;
    int row = (bh << 1) + i;
    int col = (bw << 1) + j;

    float fp = (float)((l4 < 8) ? row : col);   // d0<32 -> row else col
    float4 iv = ((const float4*)invf)[l4 & 7];

    float s0, c0, s1, c1, s2, c2, s3, c3;
    __sincosf(fp * iv.x, &s0, &c0);
    __sincosf(fp * iv.y, &s1, &c1);
    __sincosf(fp * iv.z, &s2, &c2);
    __sincosf(fp * iv.w, &s3, &c3);
    float4 cv = {c0, c1, c2, c3};
    float4 sv = {s0, s1, s2, s3};

    size_t base = (size_t)(OFF + tok) * 128 + (l4 << 2);
    #pragma unroll
    for (int f = 0; f < T; ++f) {
        size_t o = base + (size_t)f * (HW * 128);
        *(float4*)(cosO + o)      = cv;   // first 64-wide half
        *(float4*)(cosO + o + 64) = cv;   // duplicated half
        *(float4*)(sinO + o)      = sv;
        *(float4*)(sinO + o + 64) = sv;
    }
}

// Block-range boundaries (all static):
//  patch: img0 4608 | img1 2592 | img2 2304 | img3 1152   (sum 10656)
//  rope : img0  256 | img1  144 | img2  128 | img3   64   (sum   592)
__global__ __launch_bounds__(256) void fused_kernel(
    const float* __restrict__ tab, const float* __restrict__ invf,
    float* __restrict__ out, float* __restrict__ cosO, float* __restrict__ sinO)
{
    int b = (int)blockIdx.x;
    if      (b < 4608)  patch_body<1, 64, 64, 0>    (b,         tab, out);
    else if (b < 7200)  patch_body<4, 48, 48, 4096> (b - 4608,  tab, out);
    else if (b < 9504)  patch_body<8, 32, 64, 13312>(b - 7200,  tab, out);
    else if (b < 10656) patch_body<16,32, 32, 29696>(b - 9504,  tab, out);
    else if (b < 10912) rope_body<1, 64, 64, 0>     (b - 10656, invf, cosO, sinO);
    else if (b < 11056) rope_body<4, 48, 48, 4096>  (b - 10912, invf, cosO, sinO);
    else if (b < 11184) rope_body<8, 32, 64, 13312> (b - 11056, invf, cosO, sinO);
    else                rope_body<16,32, 32, 29696> (b - 11184, invf, cosO, sinO);
}

extern "C" void kernel_launch(void* const* d_in, const int* in_sizes, int n_in,
                              void* d_out, int out_size, void* d_ws, size_t ws_size,
                              hipStream_t stream) {
    const float* tab  = (const float*)d_in[1];   // [1225, 1152]
    const float* invf = (const float*)d_in[2];   // [32]
    float* out = (float*)d_out;

    constexpr size_t NTOK = 46080;
    float* cosO = out + NTOK * 1152;
    float* sinO = cosO + NTOK * 128;

    fused_kernel<<<11248, 256, 0, stream>>>(tab, invf, out, cosO, sinO);
}

// Round 5
// 57.404 us; speedup vs baseline: 1.9438x; 1.0172x over previous
//
#include <hip/hip_runtime.h>

// ---------------------------------------------------------------------------
// Model_51453708206406: fast_pos_embed_interpolate + MRoPE cos/sin (f32 out).
// Outputs concatenated: [46080,1152] pe | [46080,128] cos | [46080,128] sin.
// Static grid: {1,64,64},{4,48,48},{8,32,64},{16,32,32}; merge m=2, G=35.
//
// Frames within an image are identical (jnp.tile over t): compute frame 0
// only (9472 unique tokens), replicate stores across t. Output stores are
// NON-TEMPORAL (nt) so the 259.5 MB write stream doesn't evict the 5.6 MB
// interpolation table from L2 — table reads then stop costing fabric BW.
// ---------------------------------------------------------------------------

typedef float fx4 __attribute__((ext_vector_type(4)));  // clang vector: valid
                                                        // for nontemporal bltn

__device__ __forceinline__ void nt_store4(float* p, fx4 v) {
    __builtin_nontemporal_store(v, (fx4*)p);
}

template <int T, int H, int W, int OFF>
__device__ __forceinline__ void patch_body(int b, const float* __restrict__ tab,
                                           float* __restrict__ out) {
    constexpr int C4 = 1152 / 4;          // 288 channel-quads
    constexpr int HW = H * W;
    constexpr int WB = W / 2;

    int idx = b * 256 + (int)threadIdx.x; // < HW*288 (exact multiple of 256)
    int tok = idx / C4;                   // frame-0 token in merged order
    int c4  = idx - tok * C4;

    // invert merged-block ordering: tok = ((bh*WB+bw)<<2)+(i<<1)+j
    int j  = tok & 1;
    int i  = (tok >> 1) & 1;
    int blk = tok >> 2;
    int bw = blk % WB;
    int bh = blk / WB;
    int row = (bh << 1) + i;
    int col = (bw << 1) + j;

    // linspace(0,34,H)[row], linspace(0,34,W)[col]
    float hx = (float)row * (float)(34.0 / (H - 1));
    float wx = (float)col * (float)(34.0 / (W - 1));
    int hf = (int)hx, wf = (int)wx;
    float dh = hx - (float)hf, dw = wx - (float)wf;
    int hc = min(hf + 1, 34), wc = min(wf + 1, 34);

    float w00 = (1.f - dh) * (1.f - dw);
    float w01 = (1.f - dh) * dw;
    float w10 = dh * (1.f - dw);
    float w11 = dh * dw;

    const fx4 a = *((const fx4*)(tab + (hf * 35 + wf) * 1152) + c4);
    const fx4 bq= *((const fx4*)(tab + (hf * 35 + wc) * 1152) + c4);
    const fx4 c = *((const fx4*)(tab + (hc * 35 + wf) * 1152) + c4);
    const fx4 d = *((const fx4*)(tab + (hc * 35 + wc) * 1152) + c4);

    fx4 o = w00 * a + w01 * bq + w10 * c + w11 * d;

    float* dst = out + (size_t)(OFF + tok) * 1152 + (c4 << 2);
    #pragma unroll
    for (int f = 0; f < T; ++f)           // frames are identical copies
        nt_store4(dst + (size_t)f * (HW * 1152), o);
}

template <int T, int H, int W, int OFF>
__device__ __forceinline__ void rope_body(int b, const float* __restrict__ invf,
                                          float* __restrict__ cosO,
                                          float* __restrict__ sinO) {
    constexpr int HW = H * W;
    constexpr int WB = W / 2;

    int idx = b * 256 + (int)threadIdx.x; // < HW*16 (exact multiple of 256)
    int tok = idx >> 4;
    int l4  = idx & 15;                   // channel-quad, d0 = 4*l4 in [0,64)

    int j  = tok & 1;
    int i  = (tok >> 1) & 1;
    int blk = tok >> 2;
    int bw = blk % WB;
    int bh = blk / WB;
    int row = (bh << 1) + i;
    int col = (bw << 1) + j;

    float fp = (float)((l4 < 8) ? row : col);   // d0<32 -> row else col
    fx4 iv = ((const fx4*)invf)[l4 & 7];

    float s0, c0, s1, c1, s2, c2, s3, c3;
    __sincosf(fp * iv.x, &s0, &c0);
    __sincosf(fp * iv.y, &s1, &c1);
    __sincosf(fp * iv.z, &s2, &c2);
    __sincosf(fp * iv.w, &s3, &c3);
    fx4 cv = {c0, c1, c2, c3};
    fx4 sv = {s0, s1, s2, s3};

    size_t base = (size_t)(OFF + tok) * 128 + (l4 << 2);
    #pragma unroll
    for (int f = 0; f < T; ++f) {
        size_t o = base + (size_t)f * (HW * 128);
        nt_store4(cosO + o,      cv);     // first 64-wide half
        nt_store4(cosO + o + 64, cv);     // duplicated half
        nt_store4(sinO + o,      sv);
        nt_store4(sinO + o + 64, sv);
    }
}

// Block-range boundaries (all static):
//  patch: img0 4608 | img1 2592 | img2 2304 | img3 1152   (sum 10656)
//  rope : img0  256 | img1  144 | img2  128 | img3   64   (sum   592)
__global__ __launch_bounds__(256) void fused_kernel(
    const float* __restrict__ tab, const float* __restrict__ invf,
    float* __restrict__ out, float* __restrict__ cosO, float* __restrict__ sinO)
{
    int b = (int)blockIdx.x;
    if      (b < 4608)  patch_body<1, 64, 64, 0>    (b,         tab, out);
    else if (b < 7200)  patch_body<4, 48, 48, 4096> (b - 4608,  tab, out);
    else if (b < 9504)  patch_body<8, 32, 64, 13312>(b - 7200,  tab, out);
    else if (b < 10656) patch_body<16,32, 32, 29696>(b - 9504,  tab, out);
    else if (b < 10912) rope_body<1, 64, 64, 0>     (b - 10656, invf, cosO, sinO);
    else if (b < 11056) rope_body<4, 48, 48, 4096>  (b - 10912, invf, cosO, sinO);
    else if (b < 11184) rope_body<8, 32, 64, 13312> (b - 11056, invf, cosO, sinO);
    else                rope_body<16,32, 32, 29696> (b - 11184, invf, cosO, sinO);
}

extern "C" void kernel_launch(void* const* d_in, const int* in_sizes, int n_in,
                              void* d_out, int out_size, void* d_ws, size_t ws_size,
                              hipStream_t stream) {
    const float* tab  = (const float*)d_in[1];   // [1225, 1152]
    const float* invf = (const float*)d_in[2];   // [32]
    float* out = (float*)d_out;

    constexpr size_t NTOK = 46080;
    float* cosO = out + NTOK * 1152;
    float* sinO = cosO + NTOK * 128;

    fused_kernel<<<11248, 256, 0, stream>>>(tab, invf, out, cosO, sinO);
}

// Round 6
// 55.957 us; speedup vs baseline: 1.9941x; 1.0259x over previous
//
#include <hip/hip_runtime.h>

// ---------------------------------------------------------------------------
// Model_51453708206406: fast_pos_embed_interpolate + MRoPE cos/sin (f32 out).
// Outputs concatenated: [46080,1152] pe | [46080,128] cos | [46080,128] sin.
// Static grid: {1,64,64},{4,48,48},{8,32,64},{16,32,32}; merge m=2, G=35.
//
// v6: load-balance fix. Rope is fully frame-split (sincos recompute is free;
// every rope thread stores exactly 64B), and block ranges are ordered
// heaviest-first (patch img3 64KB/blk ... patch img0 4KB/blk) so the
// long-running blocks start at t=0 instead of forming a low-occupancy tail.
// Patch keeps frame-dedup (table reads stay at 175 MB).
// ---------------------------------------------------------------------------

typedef float fx4 __attribute__((ext_vector_type(4)));

__device__ __forceinline__ void nt_store4(float* p, fx4 v) {
    __builtin_nontemporal_store(v, (fx4*)p);
}

template <int T, int H, int W, int OFF>
__device__ __forceinline__ void patch_body(int b, const float* __restrict__ tab,
                                           float* __restrict__ out) {
    constexpr int C4 = 1152 / 4;          // 288 channel-quads
    constexpr int HW = H * W;
    constexpr int WB = W / 2;

    int idx = b * 256 + (int)threadIdx.x; // < HW*288 (exact multiple of 256)
    int tok = idx / C4;                   // frame-0 token in merged order
    int c4  = idx - tok * C4;

    // invert merged-block ordering: tok = ((bh*WB+bw)<<2)+(i<<1)+j
    int j  = tok & 1;
    int i  = (tok >> 1) & 1;
    int blk = tok >> 2;
    int bw = blk % WB;
    int bh = blk / WB;
    int row = (bh << 1) + i;
    int col = (bw << 1) + j;

    // linspace(0,34,H)[row], linspace(0,34,W)[col]
    float hx = (float)row * (float)(34.0 / (H - 1));
    float wx = (float)col * (float)(34.0 / (W - 1));
    int hf = (int)hx, wf = (int)wx;
    float dh = hx - (float)hf, dw = wx - (float)wf;
    int hc = min(hf + 1, 34), wc = min(wf + 1, 34);

    float w00 = (1.f - dh) * (1.f - dw);
    float w01 = (1.f - dh) * dw;
    float w10 = dh * (1.f - dw);
    float w11 = dh * dw;

    const fx4 a = *((const fx4*)(tab + (hf * 35 + wf) * 1152) + c4);
    const fx4 bq= *((const fx4*)(tab + (hf * 35 + wc) * 1152) + c4);
    const fx4 c = *((const fx4*)(tab + (hc * 35 + wf) * 1152) + c4);
    const fx4 d = *((const fx4*)(tab + (hc * 35 + wc) * 1152) + c4);

    fx4 o = w00 * a + w01 * bq + w10 * c + w11 * d;

    float* dst = out + (size_t)(OFF + tok) * 1152 + (c4 << 2);
    #pragma unroll
    for (int f = 0; f < T; ++f)           // frames are identical copies
        nt_store4(dst + (size_t)f * (HW * 1152), o);
}

// Fully frame-split rope: idx covers ALL T*H*W tokens of the image; each
// thread handles one (token, channel-quad) -> 4 x 16B stores (64B).
template <int T, int H, int W, int OFF>
__device__ __forceinline__ void rope_body(int b, const float* __restrict__ invf,
                                          float* __restrict__ cosO,
                                          float* __restrict__ sinO) {
    constexpr int HW = H * W;
    constexpr int WB = W / 2;

    int idx = b * 256 + (int)threadIdx.x; // < T*HW*16 (exact multiple of 256)
    int tok = idx >> 4;                   // global token within this image
    int l4  = idx & 15;                   // channel-quad, d0 = 4*l4 in [0,64)
    int rem = tok % HW;                   // frame-local (frames identical)

    int j  = rem & 1;
    int i  = (rem >> 1) & 1;
    int blk = rem >> 2;
    int bw = blk % WB;
    int bh = blk / WB;
    int row = (bh << 1) + i;
    int col = (bw << 1) + j;

    float fp = (float)((l4 < 8) ? row : col);   // d0<32 -> row else col
    fx4 iv = ((const fx4*)invf)[l4 & 7];

    float s0, c0, s1, c1, s2, c2, s3, c3;
    __sincosf(fp * iv.x, &s0, &c0);
    __sincosf(fp * iv.y, &s1, &c1);
    __sincosf(fp * iv.z, &s2, &c2);
    __sincosf(fp * iv.w, &s3, &c3);
    fx4 cv = {c0, c1, c2, c3};
    fx4 sv = {s0, s1, s2, s3};

    size_t base = (size_t)(OFF + tok) * 128 + (l4 << 2);
    nt_store4(cosO + base,      cv);      // first 64-wide half
    nt_store4(cosO + base + 64, cv);      // duplicated half
    nt_store4(sinO + base,      sv);
    nt_store4(sinO + base + 64, sv);
}

// Block ranges, heaviest-first (bytes stored per block):
//  patch3 1152 @64KB | patch2 2304 @32KB | patch1 2592 @16KB |
//  rope3 1024 @16KB | rope2 1024 @16KB | rope1 576 @16KB | rope0 256 @16KB |
//  patch0 4608 @4KB            (total 13536 blocks)
__global__ __launch_bounds__(256) void fused_kernel(
    const float* __restrict__ tab, const float* __restrict__ invf,
    float* __restrict__ out, float* __restrict__ cosO, float* __restrict__ sinO)
{
    int b = (int)blockIdx.x;
    if      (b < 1152)  patch_body<16,32, 32, 29696>(b,         tab, out);
    else if (b < 3456)  patch_body<8, 32, 64, 13312>(b - 1152,  tab, out);
    else if (b < 6048)  patch_body<4, 48, 48, 4096> (b - 3456,  tab, out);
    else if (b < 7072)  rope_body<16,32, 32, 29696> (b - 6048,  invf, cosO, sinO);
    else if (b < 8096)  rope_body<8, 32, 64, 13312> (b - 7072,  invf, cosO, sinO);
    else if (b < 8672)  rope_body<4, 48, 48, 4096>  (b - 8096,  invf, cosO, sinO);
    else if (b < 8928)  rope_body<1, 64, 64, 0>     (b - 8672,  invf, cosO, sinO);
    else                patch_body<1, 64, 64, 0>    (b - 8928,  tab, out);
}

extern "C" void kernel_launch(void* const* d_in, const int* in_sizes, int n_in,
                              void* d_out, int out_size, void* d_ws, size_t ws_size,
                              hipStream_t stream) {
    const float* tab  = (const float*)d_in[1];   // [1225, 1152]
    const float* invf = (const float*)d_in[2];   // [32]
    float* out = (float*)d_out;

    constexpr size_t NTOK = 46080;
    float* cosO = out + NTOK * 1152;
    float* sinO = cosO + NTOK * 128;

    fused_kernel<<<13536, 256, 0, stream>>>(tab, invf, out, cosO, sinO);
}